// Round 5
// baseline (12919.122 us; speedup 1.0000x reference)
//
#include <hip/hip_runtime.h>
#include <hip/hip_bf16.h>

// 2-layer LSTM (B=256,T=512,IN=H=256) + FC(128) + log_softmax on MI355X.
//
// v5: INTRA-WORKGROUP recurrence. 32 wgs x 1024 threads: wg = (batch-tile of
// 16 rows) x (role: layer0/layer1). Each wg's 16 waves hold the layer's FULL
// W_ih|W_hh in fp16 VGPR A-frags (256 VGPR/lane); h recurrence stays inside
// the wg via LDS double buffers + ONE __syncthreads per step (no cross-wg
// fences -- round-4 counters showed the 8-wg agent-fence exchange cost
// ~30k cy/step, WRITE_SIZE 490MB from per-step wbl2).
// Layer0 -> layer1 h1 stream: relaxed agent-scope atomics (MALL-coherent
// sc1 ops, no cache-wide fences), flag-gated, consumer trails ~3 steps.
// fp16 matmuls (no fp32 MFMA on CDNA4), fp32 gate math/cell state.

using u16 = unsigned short;
using u32 = unsigned int;
using u64 = unsigned long long;
typedef __attribute__((ext_vector_type(8))) _Float16 f16x8;  // 8 f16 = 4 VGPR
typedef __attribute__((ext_vector_type(4))) float f32x4;

#define T_SEQ  512
#define HDIM   256
#define LPITCH 264   // LDS row pitch in f16 units (528B) -> breaks pow2 bank stride

__device__ __forceinline__ float sigf(float x)  { return 1.0f / (1.0f + __expf(-x)); }
__device__ __forceinline__ float tanhf_(float x){ return 1.0f - 2.0f / (__expf(2.0f*x) + 1.0f); }
__device__ __forceinline__ f32x4 mfma16(f16x8 a, f16x8 b, f32x4 c) {
  return __builtin_amdgcn_mfma_f32_16x16x32_f16(a, b, c, 0, 0, 0);
}
__device__ __forceinline__ f16x8 packh(float4 a, float4 b) {
  f16x8 r;
  r[0]=(_Float16)a.x; r[1]=(_Float16)a.y; r[2]=(_Float16)a.z; r[3]=(_Float16)a.w;
  r[4]=(_Float16)b.x; r[5]=(_Float16)b.y; r[6]=(_Float16)b.z; r[7]=(_Float16)b.w;
  return r;
}

__global__ __launch_bounds__(1024, 1)
void lstm_pipe(const float* __restrict__ x,
               const float* __restrict__ w_ih0, const float* __restrict__ w_hh0,
               const float* __restrict__ b_ih0, const float* __restrict__ b_hh0,
               const float* __restrict__ w_ih1, const float* __restrict__ w_hh1,
               const float* __restrict__ b_ih1, const float* __restrict__ b_hh1,
               u16* __restrict__ h1,              // [256][512][256] f16 bits
               float* __restrict__ h2_last,       // [256][256] f32
               u32* __restrict__ flags)           // flags[bt]: h1(0..v-1) visible
{
  const int tid  = threadIdx.x;
  const int bx   = blockIdx.x;
  const int role = bx & 1;             // 0: layer0 (producer), 1: layer1
  const int bt   = bx >> 1;            // batch tile (16 rows)
  const int lane = tid & 63;
  const int wv   = tid >> 6;           // wave 0..15
  const int r16  = lane & 15;          // MFMA row/col-in-tile & batch lane
  const int q    = lane >> 4;          // 0..3

  __shared__ u16 u_lds[2][16 * LPITCH];   // u(t) staging (x or h1), f16 bits
  __shared__ u16 h_lds[2][16 * LPITCH];   // own h(t) double buffer, f16 bits

  const float* w_ih = role ? w_ih1 : w_ih0;
  const float* w_hh = role ? w_hh1 : w_hh0;
  const float* b_ih = role ? b_ih1 : b_ih0;
  const float* b_hh = role ? b_hh1 : b_hh0;

  // ---- weights -> fp16 VGPR A-frags (held all kernel) -------------------
  // wave wv owns MFMA n-tiles T = wv*4+nt (nt 0..3); gate-row n = T*16+r
  // maps to j = T*4 + (n>>2)... per the gate-interleaved order n = j*4+gate,
  // so a lane's 4 acc regs are exactly (i,f,g,o) of one (b, j=T*4+q).
  f16x8 wih[4][8], whh[4][8];          // [nt][kt] ; 256 VGPRs
  float bias[4][4], cst[4];
  #pragma unroll
  for (int nt = 0; nt < 4; ++nt) {
    const int T    = wv*4 + nt;
    const int gate = r16 & 3;
    const int jl   = T*4 + (r16 >> 2);       // j of the A-row this lane feeds
    const int grow = gate*256 + jl;          // row in w_ih/w_hh
    #pragma unroll
    for (int kt = 0; kt < 8; ++kt) {
      const int k0 = kt*32 + q*8;            // 8 contiguous k per lane
      const float* pi = w_ih + (size_t)grow*HDIM + k0;
      const float* ph = w_hh + (size_t)grow*HDIM + k0;
      wih[nt][kt] = packh(*(const float4*)pi, *(const float4*)(pi+4));
      whh[nt][kt] = packh(*(const float4*)ph, *(const float4*)(ph+4));
    }
    #pragma unroll
    for (int r = 0; r < 4; ++r) {            // acc reg r -> gate r of j=T*4+q
      const int row = r*256 + T*4 + q;
      bias[nt][r] = b_ih[row] + b_hh[row];
    }
    cst[nt] = 0.f;
  }

  // staging map: threads 0..511 move one 16B chunk of the 16x256 f16 tile
  const int sb  = tid >> 5;              // staging batch row 0..15
  const int sc8 = (tid & 31) * 8;        // f16 offset 0..248
  const int bgs = bt*16 + sb;
  u32* myflag = flags + bt;

  // ---- prologue: stage u(0) --------------------------------------------
  if (role == 0) {
    if (tid < 512) {
      const float* xp = x + (size_t)bgs*T_SEQ*HDIM + sc8;
      *(f16x8*)&u_lds[0][sb*LPITCH + sc8] =
          packh(*(const float4*)xp, *(const float4*)(xp+4));
    }
  } else {
    if (tid < 512) {
      while (__hip_atomic_load(myflag, __ATOMIC_RELAXED, __HIP_MEMORY_SCOPE_AGENT) < 1u)
        __builtin_amdgcn_s_sleep(2);
      const u64* p = (const u64*)(h1 + (size_t)bgs*T_SEQ*HDIM + sc8);
      u64 q0 = __hip_atomic_load(p,   __ATOMIC_RELAXED, __HIP_MEMORY_SCOPE_AGENT);
      u64 q1 = __hip_atomic_load(p+1, __ATOMIC_RELAXED, __HIP_MEMORY_SCOPE_AGENT);
      uint4 v; v.x=(u32)q0; v.y=(u32)(q0>>32); v.z=(u32)q1; v.w=(u32)(q1>>32);
      *(uint4*)&u_lds[0][sb*LPITCH + sc8] = v;
    }
  }
  __syncthreads();

  #pragma unroll 1
  for (int t = 0; t < T_SEQ; ++t) {
    const int cb = t & 1, pb = cb ^ 1;   // cur / prev-and-next LDS buffer

    // ---- side work (off the MFMA critical path) ------------------------
    float4 xa, xb;                       // role0 tid<512: x(t+1) prefetch
    u64 q0 = 0, q1 = 0;                  // role1 tid<512: h1(t+1) prefetch
    if (role == 0) {
      if (tid == 0 && t >= 2)            // h1(t-2) stores ack'd by barrier(t-1)
        __hip_atomic_store(myflag, (u32)(t-1), __ATOMIC_RELAXED, __HIP_MEMORY_SCOPE_AGENT);
      if (tid >= 512) {                  // waves 8-15: publish h1(t-1)
        if (t >= 1) {
          const int pi2 = tid - 512, b = pi2 >> 5, c8 = (pi2 & 31)*8;
          uint4 v = *(const uint4*)&h_lds[pb][b*LPITCH + c8];
          u64* dst = (u64*)(h1 + ((size_t)(bt*16+b)*T_SEQ + (t-1))*HDIM + c8);
          __hip_atomic_store(dst,   ((u64)v.y<<32)|v.x, __ATOMIC_RELAXED, __HIP_MEMORY_SCOPE_AGENT);
          __hip_atomic_store(dst+1, ((u64)v.w<<32)|v.z, __ATOMIC_RELAXED, __HIP_MEMORY_SCOPE_AGENT);
        }
      } else if (t < T_SEQ-1) {          // waves 0-7: x(t+1) loads (HBM latency
        const float* xp = x + ((size_t)bgs*T_SEQ + (t+1))*HDIM + sc8;  // hides under MFMAs)
        xa = *(const float4*)xp; xb = *(const float4*)(xp+4);
      }
    } else if (tid < 512 && t < T_SEQ-1) {
      // steady state: producer leads ~3 steps -> poll exits immediately
      while (__hip_atomic_load(myflag, __ATOMIC_RELAXED, __HIP_MEMORY_SCOPE_AGENT) < (u32)(t+2))
        __builtin_amdgcn_s_sleep(2);
      const u64* p = (const u64*)(h1 + ((size_t)bgs*T_SEQ + (t+1))*HDIM + sc8);
      q0 = __hip_atomic_load(p,   __ATOMIC_RELAXED, __HIP_MEMORY_SCOPE_AGENT);
      q1 = __hip_atomic_load(p+1, __ATOMIC_RELAXED, __HIP_MEMORY_SCOPE_AGENT);
    }

    // ---- gates: acc = bias + Wih*u(t) + Whh*h(t-1) ---------------------
    f32x4 acc[4];
    #pragma unroll
    for (int nt = 0; nt < 4; ++nt) {
      acc[nt][0]=bias[nt][0]; acc[nt][1]=bias[nt][1];
      acc[nt][2]=bias[nt][2]; acc[nt][3]=bias[nt][3];
    }
    const u16* ub = &u_lds[cb][r16*LPITCH + q*8];  // B-frag: col=r16(batch), k=q*8+e
    const u16* hb = &h_lds[pb][r16*LPITCH + q*8];
    #pragma unroll
    for (int kt = 0; kt < 8; ++kt) {
      f16x8 uf = *(const f16x8*)(ub + kt*32);
      acc[0]=mfma16(wih[0][kt],uf,acc[0]); acc[1]=mfma16(wih[1][kt],uf,acc[1]);
      acc[2]=mfma16(wih[2][kt],uf,acc[2]); acc[3]=mfma16(wih[3][kt],uf,acc[3]);
      if (t > 0) {
        f16x8 hf = *(const f16x8*)(hb + kt*32);
        acc[0]=mfma16(whh[0][kt],hf,acc[0]); acc[1]=mfma16(whh[1][kt],hf,acc[1]);
        acc[2]=mfma16(whh[2][kt],hf,acc[2]); acc[3]=mfma16(whh[3][kt],hf,acc[3]);
      }
    }

    // ---- LSTM cell (fp32) + h(t) -> LDS --------------------------------
    #pragma unroll
    for (int nt = 0; nt < 4; ++nt) {
      float i = sigf(acc[nt][0]), f = sigf(acc[nt][1]);
      float g = tanhf_(acc[nt][2]), o = sigf(acc[nt][3]);
      cst[nt] = f*cst[nt] + i*g;
      float hn = o * tanhf_(cst[nt]);
      const int j = wv*16 + nt*4 + q;
      _Float16 hh = (_Float16)hn;
      h_lds[cb][r16*LPITCH + j] = __builtin_bit_cast(u16, hh);
      if (role == 1 && t == T_SEQ-1)
        h2_last[(size_t)(bt*16+r16)*HDIM + j] = hn;
    }

    // ---- write u(t+1) staging into the other buffer --------------------
    if (tid < 512 && t < T_SEQ-1) {
      if (role == 0) {
        *(f16x8*)&u_lds[pb][sb*LPITCH + sc8] = packh(xa, xb);
      } else {
        uint4 v; v.x=(u32)q0; v.y=(u32)(q0>>32); v.z=(u32)q1; v.w=(u32)(q1>>32);
        *(uint4*)&u_lds[pb][sb*LPITCH + sc8] = v;
      }
    }
    __syncthreads();   // h(t) + u(t+1) complete; publish stores ack'd
  }

  // ---- epilogue (role0): publish h1(T-1), final flag -------------------
  if (role == 0) {
    if (tid >= 512) {
      const int pi2 = tid - 512, b = pi2 >> 5, c8 = (pi2 & 31)*8;
      uint4 v = *(const uint4*)&h_lds[(T_SEQ-1)&1][b*LPITCH + c8];
      u64* dst = (u64*)(h1 + ((size_t)(bt*16+b)*T_SEQ + (T_SEQ-1))*HDIM + c8);
      __hip_atomic_store(dst,   ((u64)v.y<<32)|v.x, __ATOMIC_RELAXED, __HIP_MEMORY_SCOPE_AGENT);
      __hip_atomic_store(dst+1, ((u64)v.w<<32)|v.z, __ATOMIC_RELAXED, __HIP_MEMORY_SCOPE_AGENT);
    }
    __syncthreads();
    if (tid == 0)
      __hip_atomic_store(myflag, (u32)(T_SEQ+1), __ATOMIC_RELAXED, __HIP_MEMORY_SCOPE_AGENT);
  }
}

__global__ __launch_bounds__(128)
void head_kernel(const float* __restrict__ h2, const float* __restrict__ w_fc,
                 const float* __restrict__ b_fc, float* __restrict__ out)
{
  const int b = blockIdx.x, c = threadIdx.x;   // 256 blocks x 128 threads
  __shared__ float hrow[256];
  __shared__ float red[128];
  hrow[c]       = h2[b*256 + c];
  hrow[c + 128] = h2[b*256 + 128 + c];
  __syncthreads();
  float acc = b_fc[c];
  const float* wr = w_fc + (size_t)c*256;
  #pragma unroll 8
  for (int j = 0; j < 256; ++j) acc += hrow[j] * wr[j];
  red[c] = acc; __syncthreads();
  for (int s = 64; s; s >>= 1) { if (c < s) red[c] = fmaxf(red[c], red[c+s]); __syncthreads(); }
  const float m = red[0]; __syncthreads();
  red[c] = __expf(acc - m); __syncthreads();
  for (int s = 64; s; s >>= 1) { if (c < s) red[c] += red[c+s]; __syncthreads(); }
  out[b*128 + c] = acc - m - __logf(red[0]);
}

extern "C" void kernel_launch(void* const* d_in, const int* in_sizes, int n_in,
                              void* d_out, int out_size, void* d_ws, size_t ws_size,
                              hipStream_t stream) {
  const float* x     = (const float*)d_in[0];
  const float* w_ih0 = (const float*)d_in[1];
  const float* w_hh0 = (const float*)d_in[2];
  const float* b_ih0 = (const float*)d_in[3];
  const float* b_hh0 = (const float*)d_in[4];
  const float* w_ih1 = (const float*)d_in[5];
  const float* w_hh1 = (const float*)d_in[6];
  const float* b_ih1 = (const float*)d_in[7];
  const float* b_hh1 = (const float*)d_in[8];
  const float* w_fc  = (const float*)d_in[9];
  const float* b_fc  = (const float*)d_in[10];
  float* out = (float*)d_out;

  // workspace layout:
  //   [0, 4 KiB)        flags  (u32[16] used)
  //   [8 KiB, 264 KiB)  h2_last fp32 [256][256]
  //   [1 MiB, 65 MiB)   h1 f16 [256][512][256]
  const size_t NEED = (1ull << 20) + (64ull << 20);
  if (ws_size < NEED) return;          // visible validation failure, not OOB

  char* ws = (char*)d_ws;
  u32*   flags = (u32*)ws;
  float* h2    = (float*)(ws + 8192);
  u16*   h1    = (u16*)(ws + (1ull << 20));

  hipMemsetAsync(flags, 0, 4096, stream);   // zero sync flags every call

  lstm_pipe<<<dim3(32), dim3(1024), 0, stream>>>(
      x, w_ih0, w_hh0, b_ih0, b_hh0, w_ih1, w_hh1, b_ih1, b_hh1,
      h1, h2, flags);
  head_kernel<<<dim3(256), dim3(128), 0, stream>>>(h2, w_fc, b_fc, out);
}

// Round 8
// 1996.269 us; speedup vs baseline: 6.4716x; 6.4716x over previous
//
#include <hip/hip_runtime.h>
#include <hip/hip_bf16.h>

// 2-layer LSTM (B=256,T=512,IN=H=256) + FC(128) + log_softmax on MI355X.
//
// v8 == v6/v7 (never ran: rounds 6-7 lost to GPU unavailability) with the
// poll backoff (s_sleep(1)) restored -- v5's HW-validated poll used sleep;
// full-rate polling from 128 wgs contends on the flag lines at the MALL.
//
//   256 wgs x 256 thr = 2 roles (layer, bx&1) x 16 batch-tiles x 8 j-tiles.
//   Weights: fp16 VGPR A-frags per wg (1/8 layer = 128 VGPR) -- v5 showed a
//   full layer can never fit one CU's 512KB register file; v5's 1024-thread
//   wg capped VGPRs at 128 -> full spill -> 1 GB HBM scratch traffic.
//   Sync: ALL cross-wg h data moves via RELAXED agent-scope (MALL-coherent)
//   u64 atomics -- no release/acquire fences (v4's per-step wbl2+inv pair
//   cost ~12.8us/step, WRITE_SIZE 490MB). Producer wave0: data stores ->
//   s_waitcnt vmcnt(0) -> relaxed flag store. Consumer: relaxed poll,
//   control-dependent data loads (pattern HW-validated by v5's h1 stream).
//   h published in producer register layout (u32 = f16 pair {j=8wv+q,
//   8wv+4+q}); consumers unscramble with v_perm_b32 while staging to LDS.

using u16 = unsigned short;
using u32 = unsigned int;
using u64 = unsigned long long;
typedef __attribute__((ext_vector_type(8))) _Float16 f16x8;  // 4 VGPR
typedef __attribute__((ext_vector_type(4))) float f32x4;

#define T_SEQ 512
#define HDIM  256
#define KPAD  264   // LDS f16 pitch (528B): <=2-way bank conflict per phase
#define PKP   20    // pack-buffer u32 pitch (80B, 16B-aligned, non-pow2)

__device__ __forceinline__ float sigf(float x)  { return 1.0f / (1.0f + __expf(-x)); }
__device__ __forceinline__ float tanhf_(float x){ return 1.0f - 2.0f / (__expf(2.0f*x) + 1.0f); }
__device__ __forceinline__ f32x4 mfma16(f16x8 a, f16x8 b, f32x4 c) {
  return __builtin_amdgcn_mfma_f32_16x16x32_f16(a, b, c, 0, 0, 0);
}
__device__ __forceinline__ f16x8 packh(float4 a, float4 b) {
  f16x8 r;
  r[0]=(_Float16)a.x; r[1]=(_Float16)a.y; r[2]=(_Float16)a.z; r[3]=(_Float16)a.w;
  r[4]=(_Float16)b.x; r[5]=(_Float16)b.y; r[6]=(_Float16)b.z; r[7]=(_Float16)b.w;
  return r;
}
// all waves poll: lanes 0..7 watch the 8 group flags (one 32B transaction);
// s_sleep(1) backoff (~64cy) bounds poll traffic without hurting latency
__device__ __forceinline__ void spin8(const u32* f, u32 tgt, int lane) {
  for (;;) {
    u32 v = (lane < 8)
      ? __hip_atomic_load(f + lane, __ATOMIC_RELAXED, __HIP_MEMORY_SCOPE_AGENT)
      : 0xFFFFFFFFu;
    if (!__any(v < tgt)) return;
    __builtin_amdgcn_s_sleep(1);
  }
}
// unscramble 4 words (f16 pairs {j+0,j+4},{j+1,j+5},{j+2,j+6},{j+3,j+7})
// into j-order f16[8] via byte permutes.
// v_perm_b32: sel byte 0..3 -> src1 bytes, 4..7 -> src0 bytes.
__device__ __forceinline__ uint4 unscr(u32 w0, u32 w1, u32 w2, u32 w3) {
  uint4 r;
  r.x = __builtin_amdgcn_perm(w1, w0, 0x05040100u);   // {j0,j1}
  r.y = __builtin_amdgcn_perm(w3, w2, 0x05040100u);   // {j2,j3}
  r.z = __builtin_amdgcn_perm(w1, w0, 0x07060302u);   // {j4,j5}
  r.w = __builtin_amdgcn_perm(w3, w2, 0x07060302u);   // {j6,j7}
  return r;
}
// load 4 u64 (scrambled 16 f16) from MALL, write j-ordered 2x b128 to LDS
__device__ __forceinline__ void stage16(const u64* p, u16* dst) {
  u64 a = __hip_atomic_load(p+0, __ATOMIC_RELAXED, __HIP_MEMORY_SCOPE_AGENT);
  u64 b = __hip_atomic_load(p+1, __ATOMIC_RELAXED, __HIP_MEMORY_SCOPE_AGENT);
  u64 c = __hip_atomic_load(p+2, __ATOMIC_RELAXED, __HIP_MEMORY_SCOPE_AGENT);
  u64 d = __hip_atomic_load(p+3, __ATOMIC_RELAXED, __HIP_MEMORY_SCOPE_AGENT);
  *(uint4*)(dst)     = unscr((u32)a, (u32)(a>>32), (u32)b, (u32)(b>>32));
  *(uint4*)(dst + 8) = unscr((u32)c, (u32)(c>>32), (u32)d, (u32)(d>>32));
}

__global__ __launch_bounds__(256, 1)
void lstm_pipe(const float* __restrict__ x,
               const float* __restrict__ w_ih0, const float* __restrict__ w_hh0,
               const float* __restrict__ b_ih0, const float* __restrict__ b_hh0,
               const float* __restrict__ w_ih1, const float* __restrict__ w_hh1,
               const float* __restrict__ b_ih1, const float* __restrict__ b_hh1,
               u64* __restrict__ h1w,            // [256][512][64] u64 (word-scrambled h1)
               u64* __restrict__ hexw,           // [2][256][64] u64 (role1 h dbuf)
               float* __restrict__ h2_last,      // [256][256] f32
               u32* __restrict__ flags)          // [role*128 + bt*8 + jt]
{
  const int tid  = threadIdx.x;
  const int bx   = blockIdx.x;
  const int role = bx & 1;
  const int bxl  = bx >> 1;
  const int bt   = bxl & 15;        // batch tile (16 rows); sync domain
  const int jt   = bxl >> 4;        // j tile (32 hidden cols)
  const int lane = tid & 63;
  const int wv   = tid >> 6;        // wave 0..3
  const int r16  = lane & 15;
  const int q    = lane >> 4;       // 0..3

  __shared__ u16 u_lds[2][16 * KPAD];
  __shared__ u16 h_lds[2][16 * KPAD];
  __shared__ u32 pk_lds[16 * PKP];

  const float* w_ih = role ? w_ih1 : w_ih0;
  const float* w_hh = role ? w_hh1 : w_hh0;
  const float* b_ih = role ? b_ih1 : b_ih0;
  const float* b_hh = role ? b_hh1 : b_hh0;

  // ---- weights -> fp16 VGPR A-frags (128 VGPR, held all kernel) ---------
  // wave wv owns n-tiles {2wv,2wv+1}; n_local = j_local*4 + gate, so a
  // lane's 4 acc regs are (i,f,g,o) of one (b, j = T*4+q).
  f16x8 wih[2][8], whh[2][8];
  float bias[2][4];
  float cst[2] = {0.f, 0.f};
  #pragma unroll
  for (int nt = 0; nt < 2; ++nt) {
    const int Tt = wv*2 + nt, nl = Tt*16 + r16;
    const int gate = nl & 3, jl = nl >> 2;
    const int grow = gate*256 + jt*32 + jl;
    #pragma unroll
    for (int kt = 0; kt < 8; ++kt) {
      const int k0 = kt*32 + q*8;
      const float* pi = w_ih + (size_t)grow*HDIM + k0;
      const float* ph = w_hh + (size_t)grow*HDIM + k0;
      wih[nt][kt] = packh(*(const float4*)pi, *(const float4*)(pi+4));
      whh[nt][kt] = packh(*(const float4*)ph, *(const float4*)(ph+4));
    }
    #pragma unroll
    for (int r = 0; r < 4; ++r) {
      const int row = r*256 + jt*32 + Tt*4 + q;
      bias[nt][r] = b_ih[row] + b_hh[row];
    }
  }

  // staging map: thread i handles (row=i>>4, 16-f16 segment seg=i&15)
  const int srow = tid >> 4, sseg = tid & 15;
  const int bgs  = bt*16 + srow;
  u32*       f_self = flags + role*128 + bt*8;
  const u32* f_up   = flags + bt*8;          // layer0 group's flags

  // ---- prologue: stage u(0) into u_lds[0] -------------------------------
  if (role == 0) {
    const float* xp = x + (size_t)bgs*T_SEQ*HDIM + sseg*16;
    *(f16x8*)&u_lds[0][srow*KPAD + sseg*16]     = packh(*(const float4*)xp,     *(const float4*)(xp+4));
    *(f16x8*)&u_lds[0][srow*KPAD + sseg*16 + 8] = packh(*(const float4*)(xp+8), *(const float4*)(xp+12));
  } else {
    spin8(f_up, 1u, lane);
    stage16(h1w + (size_t)bgs*T_SEQ*64 + sseg*4, &u_lds[0][srow*KPAD + sseg*16]);
  }

  #pragma unroll 1
  for (int t = 0; t < T_SEQ; ++t) {
    const int cb = t & 1, nb = cb ^ 1;
    // ---- stage phase ---------------------------------------------------
    float4 xa0, xa1, xa2, xa3;
    if (role == 0 && t < T_SEQ-1) {          // issue x(t+1) loads early
      const float* xp = x + ((size_t)bgs*T_SEQ + t+1)*HDIM + sseg*16;
      xa0 = *(const float4*)xp;     xa1 = *(const float4*)(xp+4);
      xa2 = *(const float4*)(xp+8); xa3 = *(const float4*)(xp+12);
    }
    if (t > 0) {                             // wait + stage h(t-1)
      spin8(f_self, (u32)t, lane);
      const u64* hp = (role == 0)
        ? h1w  + ((size_t)bgs*T_SEQ + (t-1))*64 + sseg*4
        : hexw + (size_t)nb*16384 + (size_t)bgs*64 + sseg*4;
      stage16(hp, &h_lds[cb][srow*KPAD + sseg*16]);
    }
    if (role == 0 && t < T_SEQ-1) {          // x(t+1) -> u_lds[nb]
      *(f16x8*)&u_lds[nb][srow*KPAD + sseg*16]     = packh(xa0, xa1);
      *(f16x8*)&u_lds[nb][srow*KPAD + sseg*16 + 8] = packh(xa2, xa3);
    }
    __syncthreads();                         // barrier 1: stages visible

    // ---- compute: g = bias + Wih*u(t) + Whh*h(t-1) ---------------------
    f32x4 acc0, acc1;
    acc0[0]=bias[0][0]; acc0[1]=bias[0][1]; acc0[2]=bias[0][2]; acc0[3]=bias[0][3];
    acc1[0]=bias[1][0]; acc1[1]=bias[1][1]; acc1[2]=bias[1][2]; acc1[3]=bias[1][3];
    const u16* ub = &u_lds[cb][r16*KPAD + q*8];
    const u16* hb = &h_lds[cb][r16*KPAD + q*8];
    #pragma unroll
    for (int kt = 0; kt < 8; ++kt) {
      f16x8 uf = *(const f16x8*)(ub + kt*32);
      acc0 = mfma16(wih[0][kt], uf, acc0);
      acc1 = mfma16(wih[1][kt], uf, acc1);
      if (t > 0) {
        f16x8 hf = *(const f16x8*)(hb + kt*32);
        acc0 = mfma16(whh[0][kt], hf, acc0);
        acc1 = mfma16(whh[1][kt], hf, acc1);
      }
    }
    // ---- cell (fp32) + pack u32 {j=8wv+q, j=8wv+4+q} -------------------
    float i0=sigf(acc0[0]), f0=sigf(acc0[1]), g0=tanhf_(acc0[2]), o0=sigf(acc0[3]);
    cst[0] = f0*cst[0] + i0*g0;
    float hn0 = o0 * tanhf_(cst[0]);
    float i1=sigf(acc1[0]), f1=sigf(acc1[1]), g1=tanhf_(acc1[2]), o1=sigf(acc1[3]);
    cst[1] = f1*cst[1] + i1*g1;
    float hn1 = o1 * tanhf_(cst[1]);
    {
      _Float16 a = (_Float16)hn0, b = (_Float16)hn1;
      pk_lds[r16*PKP + wv*4 + q] =
          (u32)__builtin_bit_cast(u16, a) | ((u32)__builtin_bit_cast(u16, b) << 16);
    }
    if (role == 1 && t == T_SEQ-1) {
      h2_last[(size_t)(bt*16+r16)*HDIM + jt*32 + wv*8 + q]     = hn0;
      h2_last[(size_t)(bt*16+r16)*HDIM + jt*32 + wv*8 + 4 + q] = hn1;
    }
    if (role == 1 && t < T_SEQ-1) {          // prefetch u(t+1)=h1(t+1)
      spin8(f_up, (u32)(t+2), lane);         // steady state: already set
      stage16(h1w + ((size_t)bgs*T_SEQ + t+1)*64 + sseg*4,
              &u_lds[nb][srow*KPAD + sseg*16]);
    }
    __syncthreads();                         // barrier 2: pk ready

    // ---- publish (wave 0): data -> vmcnt(0) -> flag --------------------
    if (wv == 0) {
      const int prow = lane >> 2, pc = lane & 3;
      uint4 v = *(const uint4*)&pk_lds[prow*PKP + pc*4];
      u64 d0 = ((u64)v.y << 32) | v.x;
      u64 d1 = ((u64)v.w << 32) | v.z;
      u64* dst = (role == 0)
        ? h1w  + ((size_t)(bt*16+prow)*T_SEQ + t)*64 + jt*8 + pc*2
        : hexw + (size_t)cb*16384 + (size_t)(bt*16+prow)*64 + jt*8 + pc*2;
      __hip_atomic_store(dst,   d0, __ATOMIC_RELAXED, __HIP_MEMORY_SCOPE_AGENT);
      __hip_atomic_store(dst+1, d1, __ATOMIC_RELAXED, __HIP_MEMORY_SCOPE_AGENT);
      asm volatile("s_waitcnt vmcnt(0)" ::: "memory");   // data ack'd at MALL
      if (lane == 0)
        __hip_atomic_store(f_self + jt, (u32)(t + 1),
                           __ATOMIC_RELAXED, __HIP_MEMORY_SCOPE_AGENT);
    }
  }
}

__global__ __launch_bounds__(128)
void head_kernel(const float* __restrict__ h2, const float* __restrict__ w_fc,
                 const float* __restrict__ b_fc, float* __restrict__ out)
{
  const int b = blockIdx.x, c = threadIdx.x;   // 256 blocks x 128 threads
  __shared__ float hrow[256];
  __shared__ float red[128];
  hrow[c]       = h2[b*256 + c];
  hrow[c + 128] = h2[b*256 + 128 + c];
  __syncthreads();
  float acc = b_fc[c];
  const float* wr = w_fc + (size_t)c*256;
  #pragma unroll 8
  for (int j = 0; j < 256; ++j) acc += hrow[j] * wr[j];
  red[c] = acc; __syncthreads();
  for (int s = 64; s; s >>= 1) { if (c < s) red[c] = fmaxf(red[c], red[c+s]); __syncthreads(); }
  const float m = red[0]; __syncthreads();
  red[c] = __expf(acc - m); __syncthreads();
  for (int s = 64; s; s >>= 1) { if (c < s) red[c] += red[c+s]; __syncthreads(); }
  out[b*128 + c] = acc - m - __logf(red[0]);
}

extern "C" void kernel_launch(void* const* d_in, const int* in_sizes, int n_in,
                              void* d_out, int out_size, void* d_ws, size_t ws_size,
                              hipStream_t stream) {
  const float* x     = (const float*)d_in[0];
  const float* w_ih0 = (const float*)d_in[1];
  const float* w_hh0 = (const float*)d_in[2];
  const float* b_ih0 = (const float*)d_in[3];
  const float* b_hh0 = (const float*)d_in[4];
  const float* w_ih1 = (const float*)d_in[5];
  const float* w_hh1 = (const float*)d_in[6];
  const float* b_ih1 = (const float*)d_in[7];
  const float* b_hh1 = (const float*)d_in[8];
  const float* w_fc  = (const float*)d_in[9];
  const float* b_fc  = (const float*)d_in[10];
  float* out = (float*)d_out;

  // workspace:
  //   [0, 4 KiB)         flags u32[256]
  //   [8 KiB, 264 KiB)   h2_last f32 [256][256]
  //   [512 KiB, 768 KiB) hexw  u64 [2][256][64]   (role1 h double buffer)
  //   [1 MiB, 65 MiB)    h1w   u64 [256][512][64] (word-scrambled h1 stream)
  const size_t NEED = (1ull << 20) + (64ull << 20);
  if (ws_size < NEED) return;          // visible validation failure, not OOB

  char* ws = (char*)d_ws;
  u32*   flags = (u32*)ws;
  float* h2    = (float*)(ws + 8192);
  u64*   hexw  = (u64*)(ws + (512ull << 10));
  u64*   h1w   = (u64*)(ws + (1ull << 20));

  hipMemsetAsync(flags, 0, 4096, stream);   // zero sync flags every call

  lstm_pipe<<<dim3(256), dim3(256), 0, stream>>>(
      x, w_ih0, w_hh0, b_ih0, b_hh0, w_ih1, w_hh1, b_ih1, b_hh1,
      h1w, hexw, h2, flags);
  head_kernel<<<dim3(256), dim3(128), 0, stream>>>(h2, w_fc, b_fc, out);
}